// Round 1
// baseline (134.072 us; speedup 1.0000x reference)
//
#include <hip/hip_runtime.h>

#define B_    512
#define IN_   256
#define H_    512
#define OUT_  64
#define NDEATH (B_ - 1)
#define NSORT  512          // NDEATH padded to pow2 for bitonic sort / bsearch
#define RTOL_ 1e-6
#define ATOL_ 1e-8
#define NBLK  256
#define NTHR  512           // R14: 8 waves/block -> 2 waves/SIMD latency hiding
#define KT    32            // K-tile (per wavegroup) -> split-K x2

typedef __attribute__((ext_vector_type(4))) double d4_t;

// agent-visible store: relaxed atomic, bypasses L2 -> lands at L3 coherence
// point. No dirty L2 lines => barriers need NO wbl2/inv fences. (R11-verified)
__device__ __forceinline__ void ast(double* p, double v) {
    __hip_atomic_store(p, v, __ATOMIC_RELAXED, __HIP_MEMORY_SCOPE_AGENT);
}

// ---------------------------------------------------------------------------
// fenceless software barrier (R11-verified protocol). nb=16 for GROUP-LOCAL
// barriers, nb=256 once before pdist.
// ---------------------------------------------------------------------------
__device__ __forceinline__ void gbar(unsigned* cnt, unsigned nb) {
    __syncthreads();
    if (threadIdx.x == 0) {
        __hip_atomic_fetch_add(cnt, 1u, __ATOMIC_RELAXED,
                               __HIP_MEMORY_SCOPE_AGENT);
        while (__hip_atomic_load(cnt, __ATOMIC_RELAXED,
                                 __HIP_MEMORY_SCOPE_AGENT) < nb)
            __builtin_amdgcn_s_sleep(2);
    }
    __syncthreads();
}

// ---------------------------------------------------------------------------
// per-block: bitonic-sort deaths into LDS, emit sorted tolerance windows.
// R14: 512 threads (1 elem/thread fill, 256 comparators/round).
// ---------------------------------------------------------------------------
__device__ void sort_windows(const float* __restrict__ deaths,
                             double* sd, double* slo, double* shi, int t) {
    if (t < NSORT) sd[t] = (t < NDEATH) ? (double)deaths[t] : 1e300;
    __syncthreads();
    for (int k = 2; k <= NSORT; k <<= 1) {
        for (int j = k >> 1; j > 0; j >>= 1) {
            if (t < 256) {
                int l = ((t & ~(j - 1)) << 1) | (t & (j - 1));   // pair (l, l+j)
                int p = l + j;
                bool up = ((l & k) == 0);
                double a = sd[l], b = sd[p];
                if ((a > b) == up) { sd[l] = b; sd[p] = a; }
            }
            __syncthreads();
        }
    }
    if (t < NSORT) {
        double d = sd[t];
        double w = ATOL_ + RTOL_ * fabs(d);
        slo[t] = d - w;
        shi[t] = d + w;
    }
    __syncthreads();
}

// ---------------------------------------------------------------------------
// f64 MFMA GEMM phase, R14: split-K x2 across wavegroups (waves 0-3: k-half 0,
// waves 4-7: k-half 1), each wavegroup double-buffered in its own LDS pair;
// single barrier per K-tile (stage writes the NEXT buffer -> disjoint from all
// concurrent reads; previous iteration's end-barrier fenced the older reads).
// Partial C's combined via LDS exchange aliased onto As. C via ast.
// ---------------------------------------------------------------------------
template <typename TIN, bool RELU>
__device__ void gemm_dev(const TIN* __restrict__ A, const float* __restrict__ W,
                         const float* __restrict__ bias, double* __restrict__ C,
                         int N, int K, int tile, int t,
                         double (&As)[2][2][KT][33], double (&Ws)[2][2][KT][33]) {
    const int lane  = t & 63;
    const int wave4 = (t >> 6) & 3;     // quarter selector (same for both wg)
    const int w2    = t >> 8;           // wavegroup = K-half
    const int tg    = t & 255;          // 256-thread-local id for staging map
    const int wm    = wave4 & 1, wn = wave4 >> 1;
    const int nbx   = N >> 5;
    const int row0  = (tile / nbx) << 5;
    const int col0  = (tile % nbx) << 5;

    const int akk   = tg & 31;          // k within A tile
    const int amm   = tg >> 5;          // base row (rows amm+8p, p=0..3)
    const int wnn   = tg & 31;          // col within W tile
    const int wkk   = tg >> 5;          // base k (k-rows wkk+8p)
    const int kbase = w2 * (K >> 1);
    const int nkt   = K >> 6;           // K-tiles per wavegroup

    TIN   ar[2][4];
    float wr[2][4];

    auto load_to = [&](int rs, int kt) {
        const int k0 = kbase + (kt << 5);
        #pragma unroll
        for (int p = 0; p < 4; ++p) {
            ar[rs][p] = A[(size_t)(row0 + amm + 8 * p) * K + k0 + akk];
            wr[rs][p] = W[(size_t)(k0 + wkk + 8 * p) * N + col0 + wnn];
        }
    };
    auto stage = [&](int rs, int buf) {
        #pragma unroll
        for (int p = 0; p < 4; ++p) {
            As[w2][buf][akk][amm + 8 * p] = (double)ar[rs][p];
            Ws[w2][buf][wkk + 8 * p][wnn] = (double)wr[rs][p];
        }
    };

    load_to(0, 0);
    if (nkt > 1) load_to(1, 1);
    stage(0, 0);
    __syncthreads();

    d4_t c4 = {0.0, 0.0, 0.0, 0.0};
    const int mrow = wm * 16 + (lane & 15);
    const int ncol = wn * 16 + (lane & 15);
    const int kq   = lane >> 4;

    for (int kt = 0; kt < nkt; ++kt) {
        const int cur = kt & 1;
        if (kt + 2 < nkt) load_to(cur, kt + 2);   // depth-2 prefetch
        #pragma unroll
        for (int ks = 0; ks < KT / 4; ++ks) {
            double av = As[w2][cur][ks * 4 + kq][mrow];
            double bv = Ws[w2][cur][ks * 4 + kq][ncol];
            c4 = __builtin_amdgcn_mfma_f64_16x16x4f64(av, bv, c4, 0, 0, 0);
        }
        if (kt + 1 < nkt) stage(cur ^ 1, cur ^ 1); // disjoint buffer: no race
        __syncthreads();                           // next buffer filled + reads fenced
    }

    // combine wavegroup partials: wg1 publishes, wg0 adds + epilogue.
    // cEx aliases As (all K-loop reads fenced by the final loop barrier).
    double (*cEx)[16][17] = (double (*)[16][17])(&As[0][0][0][0]);
    const int r4 = (lane >> 4) * 4;
    if (w2 == 1) {
        #pragma unroll
        for (int r = 0; r < 4; ++r)
            cEx[wave4][r4 + r][lane & 15] = c4[r];
    }
    __syncthreads();
    if (w2 == 0) {
        #pragma unroll
        for (int r = 0; r < 4; ++r) {
            int row = row0 + wm * 16 + r4 + r;
            int col = col0 + wn * 16 + (lane & 15);
            double v = c4[r] + cEx[wave4][r4 + r][lane & 15] + (double)bias[col];
            if (RELU) v = v > 0.0 ? v : 0.0;
            ast(&C[(size_t)row * N + col], v);
        }
    }
}

// ---------------------------------------------------------------------------
// column c: mean + target-MSE partial + compactness partial -> global slots
// R14: 512 threads, one row per thread.
// ---------------------------------------------------------------------------
__device__ void mc_dev(const float* __restrict__ target,
                       const double* __restrict__ y,
                       double* __restrict__ t_part, double* __restrict__ c_part,
                       int c, int t) {
    const int wave = t >> 6, lane = t & 63;
    double v = y[(size_t)t * OUT_ + c];
    double s = v;
    for (int off = 32; off; off >>= 1) s += __shfl_down(s, off);
    __shared__ double swm[8];
    __shared__ double smean;
    if (lane == 0) swm[wave] = s;
    __syncthreads();
    if (t == 0) {
        double m = 0.0;
        #pragma unroll
        for (int w = 0; w < 8; ++w) m += swm[w];
        smean = m / (double)B_;
    }
    __syncthreads();
    double m = smean;
    double d = (double)target[(size_t)t * OUT_ + c] - v;
    double t_s = d * d;
    double c_s = fabs(v - m);
    for (int off = 32; off; off >>= 1) {
        t_s += __shfl_down(t_s, off);
        c_s += __shfl_down(c_s, off);
    }
    __shared__ double st[8], sc[8];
    if (lane == 0) { st[wave] = t_s; sc[wave] = c_s; }
    __syncthreads();
    if (t == 0) {
        double ts = 0.0, cs = 0.0;
        #pragma unroll
        for (int w = 0; w < 8; ++w) { ts += st[w]; cs += sc[w]; }
        ast(&t_part[c], ts);
        ast(&c_part[c], cs);
    }
}

// ---------------------------------------------------------------------------
// pdist + sorted-window match. Block b: rows b and 510-b (512 pairs, balanced).
// Match: lo/hi increasing => pd in any window <=> hi[ub-1] >= pd.
// ---------------------------------------------------------------------------
__device__ __forceinline__ double pair_val(const double* __restrict__ yrow_s,
                                           const double* __restrict__ yj,
                                           const double* __restrict__ slo,
                                           const double* __restrict__ shi) {
    double s = 0.0;
    #pragma unroll
    for (int d = 0; d < OUT_; d += 2) {
        double2 v = *(const double2*)(yj + d);
        double d0 = yrow_s[d]     - v.x;
        double d1 = yrow_s[d + 1] - v.y;
        s = fma(d0, d0, s);
        s = fma(d1, d1, s);
    }
    double pd = sqrt(s);
    int pos = 0;
    #pragma unroll
    for (int step = NSORT / 2; step; step >>= 1) {
        if (slo[pos + step - 1] <= pd) pos += step;
    }
    bool m = (pos > 0) && (shi[pos - 1] >= pd);
    return m ? pd : 0.0;
}

__device__ void pdist_dev(const double* __restrict__ y,
                          double* __restrict__ hom_part, int bid, int t,
                          double* yA, double* yB,
                          const double* slo, const double* shi) {
    const int iA = bid;
    const int iB = 510 - bid;     // == iA when bid == 255
    if (t < OUT_)            yA[t]        = y[(size_t)iA * OUT_ + t];
    else if (t < 2 * OUT_)   yB[t - OUT_] = y[(size_t)iB * OUT_ + (t - OUT_)];
    __syncthreads();

    double local = 0.0;
    for (int j = iA + 1 + t; j < B_; j += NTHR)
        local += pair_val(yA, y + (size_t)j * OUT_, slo, shi);
    if (iB != iA)
        for (int j = iB + 1 + t; j < B_; j += NTHR)
            local += pair_val(yB, y + (size_t)j * OUT_, slo, shi);

    for (int off = 32; off; off >>= 1) local += __shfl_down(local, off);
    __shared__ double sw[8];
    int wave = t >> 6, lane = t & 63;
    if (lane == 0) sw[wave] = local;
    __syncthreads();
    if (t == 0) {
        double s = 0.0;
        #pragma unroll
        for (int w = 0; w < 8; ++w) s += sw[w];
        ast(&hom_part[bid], s);
    }
}

// ---------------------------------------------------------------------------
// single fused persistent kernel, R14: 256 blocks x 512 threads (2 waves/SIMD).
// 16 groups of 16 blocks; group g owns row-strip g through the whole MLP;
// phases P0..P2 sync with GROUP-LOCAL 16-arrival barriers; one global barrier
// before pdist. Counter layout (uints): grp g phase p -> cnt[g*32+p];
// global -> cnt[512]; finalize -> cnt[544].
// ---------------------------------------------------------------------------
__global__ __launch_bounds__(NTHR) void fused_k(
    const float* __restrict__ batch, const float* __restrict__ target,
    const float* __restrict__ W1, const float* __restrict__ b1,
    const float* __restrict__ W2, const float* __restrict__ b2,
    const float* __restrict__ W3, const float* __restrict__ b3,
    const float* __restrict__ Wout, const float* __restrict__ bout,
    const float* __restrict__ deaths, float* __restrict__ out,
    double* __restrict__ hA, double* __restrict__ hB,
    double* __restrict__ hC, double* __restrict__ yv,
    double* __restrict__ hom_part, double* __restrict__ t_part,
    double* __restrict__ c_part, unsigned* __restrict__ cnt) {
    const int bid = blockIdx.x;
    const int t   = threadIdx.x;
    const int g   = bid >> 4;     // group = row-strip
    const int c   = bid & 15;     // col-tile within group
    unsigned* gc  = cnt + g * 32; // group-private counter line

    __shared__ double As[2][2][KT][33];
    __shared__ double Ws[2][2][KT][33];
    __shared__ double slo[NSORT], shi[NSORT];
    __shared__ double yA[OUT_], yB[OUT_];
    __shared__ int    lastf;
    double* sd = &As[0][0][0][0];             // sort scratch alias (512 dbl)

    // P0..P2: three 512x512 GEMMs; tile = bid (row0=32g, col0=32c).
    gemm_dev<float,  true>(batch, W1, b1, hA, H_, IN_, bid, t, As, Ws);
    gbar(&gc[0], 16);
    gemm_dev<double, true>(hA, W2, b2, hB, H_, H_, bid, t, As, Ws);
    gbar(&gc[1], 16);
    gemm_dev<double, true>(hB, W3, b3, hC, H_, H_, bid, t, As, Ws);
    gbar(&gc[2], 16);

    // P3: Wout tile g*2+c on c<2 (row-strip g -> group-local dep); c>=2 sort
    if (c < 2) gemm_dev<double, false>(hC, Wout, bout, yv, OUT_, H_, g * 2 + c, t, As, Ws);
    else       sort_windows(deaths, sd, slo, shi, t);

    // single global barrier: pdist needs all of yv
    gbar(&cnt[512], NBLK);
    if (c < 2) sort_windows(deaths, sd, slo, shi, t);

    // P4: pdist on all 256 blocks; mean/MSE/compactness on blocks 0..63
    pdist_dev(yv, hom_part, bid, t, yA, yB, slo, shi);
    if (bid < OUT_) mc_dev(target, yv, t_part, c_part, bid, t);

    // P5: last block to arrive finalizes
    __syncthreads();
    if (t == 0) {
        unsigned prev = __hip_atomic_fetch_add(&cnt[544], 1u, __ATOMIC_RELAXED,
                                               __HIP_MEMORY_SCOPE_AGENT);
        lastf = (prev == NBLK - 1);
    }
    __syncthreads();
    if (lastf) {
        double h = 0.0, tp = 0.0, cp = 0.0;
        if (t < NBLK)
            h = __hip_atomic_load(&hom_part[t], __ATOMIC_RELAXED,
                                  __HIP_MEMORY_SCOPE_AGENT);
        if (t < OUT_) {
            tp = __hip_atomic_load(&t_part[t], __ATOMIC_RELAXED,
                                   __HIP_MEMORY_SCOPE_AGENT);
            cp = __hip_atomic_load(&c_part[t], __ATOMIC_RELAXED,
                                   __HIP_MEMORY_SCOPE_AGENT);
        }
        for (int off = 32; off; off >>= 1) {
            h  += __shfl_down(h,  off);
            tp += __shfl_down(tp, off);
            cp += __shfl_down(cp, off);
        }
        __shared__ double sh[8], stp[8], scp[8];
        int wave = t >> 6, lane = t & 63;
        if (lane == 0) { sh[wave] = h; stp[wave] = tp; scp[wave] = cp; }
        __syncthreads();
        if (t == 0) {
            double hs = 0.0, ts = 0.0, cs = 0.0;
            #pragma unroll
            for (int w = 0; w < 8; ++w) {
                hs += sh[w]; ts += stp[w]; cs += scp[w];
            }
            out[0] = (float)(ts / (double)(B_ * OUT_) + hs + 0.01 * cs);
        }
    }
}

extern "C" void kernel_launch(void* const* d_in, const int* in_sizes, int n_in,
                              void* d_out, int out_size, void* d_ws, size_t ws_size,
                              hipStream_t stream) {
    const float* batch  = (const float*)d_in[0];
    const float* target = (const float*)d_in[1];
    const float* W1     = (const float*)d_in[2];
    const float* b1     = (const float*)d_in[3];
    const float* W2     = (const float*)d_in[4];
    const float* b2     = (const float*)d_in[5];
    const float* W3     = (const float*)d_in[6];
    const float* b3     = (const float*)d_in[7];
    const float* Wout   = (const float*)d_in[8];
    const float* bout   = (const float*)d_in[9];
    const float* deaths = (const float*)d_in[10];
    float* out = (float*)d_out;

    double* hA       = (double*)d_ws;              // 512*512
    double* hB       = hA + (size_t)B_ * H_;       // 512*512
    double* hC       = hB + (size_t)B_ * H_;       // 512*512
    double* yv       = hC + (size_t)B_ * H_;       // 512*64
    double* hom_part = yv + (size_t)B_ * OUT_;     // 256
    double* t_part   = hom_part + NBLK;            // 64
    double* c_part   = t_part + OUT_;              // 64
    unsigned* cnt    = (unsigned*)(c_part + OUT_); // 576 uints

    hipMemsetAsync(cnt, 0, 576 * sizeof(unsigned), stream);

    fused_k<<<dim3(NBLK), dim3(NTHR), 0, stream>>>(
        batch, target, W1, b1, W2, b2, W3, b3, Wout, bout, deaths, out,
        hA, hB, hC, yv, hom_part, t_part, c_part, cnt);
}

// Round 2
// 129.973 us; speedup vs baseline: 1.0315x; 1.0315x over previous
//
#include <hip/hip_runtime.h>

#define B_    512
#define IN_   256
#define H_    512
#define OUT_  64
#define NDEATH (B_ - 1)
#define NSORT  512          // NDEATH padded to pow2 for bitonic sort / bsearch
#define RTOL_ 1e-6
#define ATOL_ 1e-8
#define NBLK  256
#define NTHR  512           // 8 waves/block -> 2 waves/SIMD
#define KT    32            // K-tile (per wavegroup), split-K x2

typedef __attribute__((ext_vector_type(4))) double d4_t;

// agent-visible store: relaxed atomic, bypasses L2 -> lands at L3 coherence
// point. No dirty L2 lines => barriers need NO wbl2/inv fences. (R11-verified)
__device__ __forceinline__ void ast(double* p, double v) {
    __hip_atomic_store(p, v, __ATOMIC_RELAXED, __HIP_MEMORY_SCOPE_AGENT);
}
__device__ __forceinline__ double ald(const double* p) {
    return __hip_atomic_load(p, __ATOMIC_RELAXED, __HIP_MEMORY_SCOPE_AGENT);
}

// ---------------------------------------------------------------------------
// R15: LDS-only barrier. __syncthreads() drains vmcnt(0) which force-completes
// the depth-2 global prefetch every K-iter (the §5 barrier-drain stall). The
// K-loop's only cross-wave dependency is LDS staging -> lgkmcnt(0)+s_barrier
// suffices; global loads feed own-wave regs (compiler inserts precise vmcnt
// waits at consumption). Prefetches now ride across barriers (counted-vmcnt
// pattern, plain HIP).
// ---------------------------------------------------------------------------
__device__ __forceinline__ void lbar() {
    asm volatile("s_waitcnt lgkmcnt(0)" ::: "memory");
    __builtin_amdgcn_s_barrier();
    asm volatile("" ::: "memory");
}

// ---------------------------------------------------------------------------
// fenceless software barrier (R11-verified protocol). nb=16 for GROUP-LOCAL
// barriers, nb=256 once before pdist. Full __syncthreads REQUIRED here: the
// vmcnt(0) drain is what makes prior ast stores visible before the counter
// increment.
// ---------------------------------------------------------------------------
__device__ __forceinline__ void gbar(unsigned* cnt, unsigned nb) {
    __syncthreads();
    if (threadIdx.x == 0) {
        __hip_atomic_fetch_add(cnt, 1u, __ATOMIC_RELAXED,
                               __HIP_MEMORY_SCOPE_AGENT);
        while (__hip_atomic_load(cnt, __ATOMIC_RELAXED,
                                 __HIP_MEMORY_SCOPE_AGENT) < nb)
            __builtin_amdgcn_s_sleep(2);
    }
    __syncthreads();
}

// ---------------------------------------------------------------------------
// per-block: bitonic-sort deaths into LDS, emit sorted tolerance windows.
// 512 threads (1 elem/thread fill, 256 comparators/round).
// ---------------------------------------------------------------------------
__device__ void sort_windows(const float* __restrict__ deaths,
                             double* sd, double* slo, double* shi, int t) {
    if (t < NSORT) sd[t] = (t < NDEATH) ? (double)deaths[t] : 1e300;
    __syncthreads();
    for (int k = 2; k <= NSORT; k <<= 1) {
        for (int j = k >> 1; j > 0; j >>= 1) {
            if (t < 256) {
                int l = ((t & ~(j - 1)) << 1) | (t & (j - 1));   // pair (l, l+j)
                int p = l + j;
                bool up = ((l & k) == 0);
                double a = sd[l], b = sd[p];
                if ((a > b) == up) { sd[l] = b; sd[p] = a; }
            }
            __syncthreads();
        }
    }
    if (t < NSORT) {
        double d = sd[t];
        double w = ATOL_ + RTOL_ * fabs(d);
        slo[t] = d - w;
        shi[t] = d + w;
    }
    __syncthreads();
}

// ---------------------------------------------------------------------------
// f64 MFMA GEMM phase: split-K x2 across wavegroups (waves 0-3: k-half 0,
// waves 4-7: k-half 1), each wavegroup double-buffered in its own LDS pair;
// ONE lgkm-only barrier per K-tile (stage writes the NEXT buffer -> disjoint
// from all concurrent reads; previous iteration's barrier fenced older reads;
// global prefetches stay in flight across barriers).
// Partial C's combined via LDS exchange aliased onto As. C via ast.
// ---------------------------------------------------------------------------
template <typename TIN, bool RELU>
__device__ void gemm_dev(const TIN* __restrict__ A, const float* __restrict__ W,
                         const float* __restrict__ bias, double* __restrict__ C,
                         int N, int K, int tile, int t,
                         double (&As)[2][2][KT][33], double (&Ws)[2][2][KT][33]) {
    const int lane  = t & 63;
    const int wave4 = (t >> 6) & 3;     // quarter selector (same for both wg)
    const int w2    = t >> 8;           // wavegroup = K-half
    const int tg    = t & 255;          // 256-thread-local id for staging map
    const int wm    = wave4 & 1, wn = wave4 >> 1;
    const int nbx   = N >> 5;
    const int row0  = (tile / nbx) << 5;
    const int col0  = (tile % nbx) << 5;

    const int akk   = tg & 31;          // k within A tile
    const int amm   = tg >> 5;          // base row (rows amm+8p, p=0..3)
    const int wnn   = tg & 31;          // col within W tile
    const int wkk   = tg >> 5;          // base k (k-rows wkk+8p)
    const int kbase = w2 * (K >> 1);
    const int nkt   = K >> 6;           // K-tiles per wavegroup

    TIN   ar[2][4];
    float wr[2][4];

    auto load_to = [&](int rs, int kt) {
        const int k0 = kbase + (kt << 5);
        #pragma unroll
        for (int p = 0; p < 4; ++p) {
            ar[rs][p] = A[(size_t)(row0 + amm + 8 * p) * K + k0 + akk];
            wr[rs][p] = W[(size_t)(k0 + wkk + 8 * p) * N + col0 + wnn];
        }
    };
    auto stage = [&](int rs, int buf) {
        #pragma unroll
        for (int p = 0; p < 4; ++p) {
            As[w2][buf][akk][amm + 8 * p] = (double)ar[rs][p];
            Ws[w2][buf][wkk + 8 * p][wnn] = (double)wr[rs][p];
        }
    };

    load_to(0, 0);
    if (nkt > 1) load_to(1, 1);
    stage(0, 0);
    lbar();

    d4_t c4 = {0.0, 0.0, 0.0, 0.0};
    const int mrow = wm * 16 + (lane & 15);
    const int ncol = wn * 16 + (lane & 15);
    const int kq   = lane >> 4;

    for (int kt = 0; kt < nkt; ++kt) {
        const int cur = kt & 1;
        if (kt + 2 < nkt) load_to(cur, kt + 2);   // depth-2 prefetch (rides barriers)
        #pragma unroll
        for (int ks = 0; ks < KT / 4; ++ks) {
            double av = As[w2][cur][ks * 4 + kq][mrow];
            double bv = Ws[w2][cur][ks * 4 + kq][ncol];
            c4 = __builtin_amdgcn_mfma_f64_16x16x4f64(av, bv, c4, 0, 0, 0);
        }
        if (kt + 1 < nkt) stage(cur ^ 1, cur ^ 1); // disjoint buffer: no race
        lbar();                                    // lgkm-only: writes visible,
    }                                              // vmcnt rides across

    // combine wavegroup partials: wg1 publishes, wg0 adds + epilogue.
    // cEx aliases As (all K-loop reads fenced by the final loop barrier).
    double (*cEx)[16][17] = (double (*)[16][17])(&As[0][0][0][0]);
    const int r4 = (lane >> 4) * 4;
    if (w2 == 1) {
        #pragma unroll
        for (int r = 0; r < 4; ++r)
            cEx[wave4][r4 + r][lane & 15] = c4[r];
    }
    lbar();
    if (w2 == 0) {
        #pragma unroll
        for (int r = 0; r < 4; ++r) {
            int row = row0 + wm * 16 + r4 + r;
            int col = col0 + wn * 16 + (lane & 15);
            double v = c4[r] + cEx[wave4][r4 + r][lane & 15] + (double)bias[col];
            if (RELU) v = v > 0.0 ? v : 0.0;
            ast(&C[(size_t)row * N + col], v);
        }
    }
}

// ---------------------------------------------------------------------------
// column c: mean + target-MSE partial + compactness partial -> global slots
// 512 threads, one row per thread.
// ---------------------------------------------------------------------------
__device__ void mc_dev(const float* __restrict__ target,
                       const double* __restrict__ y,
                       double* __restrict__ t_part, double* __restrict__ c_part,
                       int c, int t) {
    const int wave = t >> 6, lane = t & 63;
    double v = y[(size_t)t * OUT_ + c];
    double s = v;
    for (int off = 32; off; off >>= 1) s += __shfl_down(s, off);
    __shared__ double swm[8];
    __shared__ double smean;
    if (lane == 0) swm[wave] = s;
    __syncthreads();
    if (t == 0) {
        double m = 0.0;
        #pragma unroll
        for (int w = 0; w < 8; ++w) m += swm[w];
        smean = m / (double)B_;
    }
    __syncthreads();
    double m = smean;
    double d = (double)target[(size_t)t * OUT_ + c] - v;
    double t_s = d * d;
    double c_s = fabs(v - m);
    for (int off = 32; off; off >>= 1) {
        t_s += __shfl_down(t_s, off);
        c_s += __shfl_down(c_s, off);
    }
    __shared__ double st[8], sc[8];
    if (lane == 0) { st[wave] = t_s; sc[wave] = c_s; }
    __syncthreads();
    if (t == 0) {
        double ts = 0.0, cs = 0.0;
        #pragma unroll
        for (int w = 0; w < 8; ++w) { ts += st[w]; cs += sc[w]; }
        ast(&t_part[c], ts);
        ast(&c_part[c], cs);
    }
}

// ---------------------------------------------------------------------------
// pdist + sorted-window match. Block b: rows b and 510-b (512 pairs, balanced).
// Match: lo/hi increasing => pd in any window <=> hi[ub-1] >= pd.
// ---------------------------------------------------------------------------
__device__ __forceinline__ double pair_val(const double* __restrict__ yrow_s,
                                           const double* __restrict__ yj,
                                           const double* __restrict__ slo,
                                           const double* __restrict__ shi) {
    double s = 0.0;
    #pragma unroll
    for (int d = 0; d < OUT_; d += 2) {
        double2 v = *(const double2*)(yj + d);
        double d0 = yrow_s[d]     - v.x;
        double d1 = yrow_s[d + 1] - v.y;
        s = fma(d0, d0, s);
        s = fma(d1, d1, s);
    }
    double pd = sqrt(s);
    int pos = 0;
    #pragma unroll
    for (int step = NSORT / 2; step; step >>= 1) {
        if (slo[pos + step - 1] <= pd) pos += step;
    }
    bool m = (pos > 0) && (shi[pos - 1] >= pd);
    return m ? pd : 0.0;
}

__device__ void pdist_dev(const double* __restrict__ y,
                          double* __restrict__ hom_part, int bid, int t,
                          double* yA, double* yB,
                          const double* slo, const double* shi) {
    const int iA = bid;
    const int iB = 510 - bid;     // == iA when bid == 255
    if (t < OUT_)            yA[t]        = y[(size_t)iA * OUT_ + t];
    else if (t < 2 * OUT_)   yB[t - OUT_] = y[(size_t)iB * OUT_ + (t - OUT_)];
    __syncthreads();

    double local = 0.0;
    for (int j = iA + 1 + t; j < B_; j += NTHR)
        local += pair_val(yA, y + (size_t)j * OUT_, slo, shi);
    if (iB != iA)
        for (int j = iB + 1 + t; j < B_; j += NTHR)
            local += pair_val(yB, y + (size_t)j * OUT_, slo, shi);

    for (int off = 32; off; off >>= 1) local += __shfl_down(local, off);
    __shared__ double sw[8];
    int wave = t >> 6, lane = t & 63;
    if (lane == 0) sw[wave] = local;
    __syncthreads();
    if (t == 0) {
        double s = 0.0;
        #pragma unroll
        for (int w = 0; w < 8; ++w) s += sw[w];
        ast(&hom_part[bid], s);
    }
}

// ---------------------------------------------------------------------------
// single fused persistent kernel, R15: 256 blocks x 512 threads.
// 16 groups of 16 blocks; group g owns row-strip g through the whole MLP;
// phases P0..P2 sync with GROUP-LOCAL 16-arrival barriers; one global barrier
// before pdist. K-loops use lgkm-only barriers (prefetch rides across).
// Block 2 broadcasts sorted windows -> c<2 blocks skip the post-barrier sort.
// Counter layout (uints): grp g phase p -> cnt[g*32+p]; global -> cnt[512];
// finalize -> cnt[544]. Window broadcast: wbc[0..511]=lo, wbc[512..1023]=hi.
// ---------------------------------------------------------------------------
__global__ __launch_bounds__(NTHR) void fused_k(
    const float* __restrict__ batch, const float* __restrict__ target,
    const float* __restrict__ W1, const float* __restrict__ b1,
    const float* __restrict__ W2, const float* __restrict__ b2,
    const float* __restrict__ W3, const float* __restrict__ b3,
    const float* __restrict__ Wout, const float* __restrict__ bout,
    const float* __restrict__ deaths, float* __restrict__ out,
    double* __restrict__ hA, double* __restrict__ hB,
    double* __restrict__ hC, double* __restrict__ yv,
    double* __restrict__ hom_part, double* __restrict__ t_part,
    double* __restrict__ c_part, unsigned* __restrict__ cnt,
    double* __restrict__ wbc) {
    const int bid = blockIdx.x;
    const int t   = threadIdx.x;
    const int g   = bid >> 4;     // group = row-strip
    const int c   = bid & 15;     // col-tile within group
    unsigned* gc  = cnt + g * 32; // group-private counter line

    __shared__ double As[2][2][KT][33];
    __shared__ double Ws[2][2][KT][33];
    __shared__ double slo[NSORT], shi[NSORT];
    __shared__ double yA[OUT_], yB[OUT_];
    __shared__ int    lastf;
    double* sd = &As[0][0][0][0];             // sort scratch alias (512 dbl)

    // P0..P2: three 512x512 GEMMs; tile = bid (row0=32g, col0=32c).
    gemm_dev<float,  true>(batch, W1, b1, hA, H_, IN_, bid, t, As, Ws);
    gbar(&gc[0], 16);
    gemm_dev<double, true>(hA, W2, b2, hB, H_, H_, bid, t, As, Ws);
    gbar(&gc[1], 16);
    gemm_dev<double, true>(hB, W3, b3, hC, H_, H_, bid, t, As, Ws);
    gbar(&gc[2], 16);

    // P3: Wout tile g*2+c on c<2 (row-strip g -> group-local dep); c>=2 sort.
    // bid==2 publishes the sorted windows for the c<2 blocks.
    if (c < 2) {
        gemm_dev<double, false>(hC, Wout, bout, yv, OUT_, H_, g * 2 + c, t, As, Ws);
    } else {
        sort_windows(deaths, sd, slo, shi, t);
        if (bid == 2 && t < NSORT) {
            ast(&wbc[t],         slo[t]);
            ast(&wbc[NSORT + t], shi[t]);
        }
    }

    // single global barrier: pdist needs all of yv (and the window broadcast)
    gbar(&cnt[512], NBLK);
    if (c < 2) {
        if (t < NSORT) {
            slo[t] = ald(&wbc[t]);
            shi[t] = ald(&wbc[NSORT + t]);
        }
        __syncthreads();
    }

    // P4: pdist on all 256 blocks; mean/MSE/compactness on blocks 0..63
    pdist_dev(yv, hom_part, bid, t, yA, yB, slo, shi);
    if (bid < OUT_) mc_dev(target, yv, t_part, c_part, bid, t);

    // P5: last block to arrive finalizes
    __syncthreads();
    if (t == 0) {
        unsigned prev = __hip_atomic_fetch_add(&cnt[544], 1u, __ATOMIC_RELAXED,
                                               __HIP_MEMORY_SCOPE_AGENT);
        lastf = (prev == NBLK - 1);
    }
    __syncthreads();
    if (lastf) {
        double h = 0.0, tp = 0.0, cp = 0.0;
        if (t < NBLK)
            h = __hip_atomic_load(&hom_part[t], __ATOMIC_RELAXED,
                                  __HIP_MEMORY_SCOPE_AGENT);
        if (t < OUT_) {
            tp = __hip_atomic_load(&t_part[t], __ATOMIC_RELAXED,
                                   __HIP_MEMORY_SCOPE_AGENT);
            cp = __hip_atomic_load(&c_part[t], __ATOMIC_RELAXED,
                                   __HIP_MEMORY_SCOPE_AGENT);
        }
        for (int off = 32; off; off >>= 1) {
            h  += __shfl_down(h,  off);
            tp += __shfl_down(tp, off);
            cp += __shfl_down(cp, off);
        }
        __shared__ double sh[8], stp[8], scp[8];
        int wave = t >> 6, lane = t & 63;
        if (lane == 0) { sh[wave] = h; stp[wave] = tp; scp[wave] = cp; }
        __syncthreads();
        if (t == 0) {
            double hs = 0.0, ts = 0.0, cs = 0.0;
            #pragma unroll
            for (int w = 0; w < 8; ++w) {
                hs += sh[w]; ts += stp[w]; cs += scp[w];
            }
            out[0] = (float)(ts / (double)(B_ * OUT_) + hs + 0.01 * cs);
        }
    }
}

extern "C" void kernel_launch(void* const* d_in, const int* in_sizes, int n_in,
                              void* d_out, int out_size, void* d_ws, size_t ws_size,
                              hipStream_t stream) {
    const float* batch  = (const float*)d_in[0];
    const float* target = (const float*)d_in[1];
    const float* W1     = (const float*)d_in[2];
    const float* b1     = (const float*)d_in[3];
    const float* W2     = (const float*)d_in[4];
    const float* b2     = (const float*)d_in[5];
    const float* W3     = (const float*)d_in[6];
    const float* b3     = (const float*)d_in[7];
    const float* Wout   = (const float*)d_in[8];
    const float* bout   = (const float*)d_in[9];
    const float* deaths = (const float*)d_in[10];
    float* out = (float*)d_out;

    double* hA       = (double*)d_ws;              // 512*512
    double* hB       = hA + (size_t)B_ * H_;       // 512*512
    double* hC       = hB + (size_t)B_ * H_;       // 512*512
    double* yv       = hC + (size_t)B_ * H_;       // 512*64
    double* hom_part = yv + (size_t)B_ * OUT_;     // 256
    double* t_part   = hom_part + NBLK;            // 64
    double* c_part   = t_part + OUT_;              // 64
    unsigned* cnt    = (unsigned*)(c_part + OUT_); // 576 uints
    double* wbc      = (double*)(cnt + 576);       // 1024 doubles (lo|hi)

    hipMemsetAsync(cnt, 0, 576 * sizeof(unsigned), stream);

    fused_k<<<dim3(NBLK), dim3(NTHR), 0, stream>>>(
        batch, target, W1, b1, W2, b2, W3, b3, Wout, bout, deaths, out,
        hA, hB, hC, yv, hom_part, t_part, c_part, cnt, wbc);
}

// Round 3
// 122.292 us; speedup vs baseline: 1.0963x; 1.0628x over previous
//
#include <hip/hip_runtime.h>

#define B_    512
#define IN_   256
#define H_    512
#define OUT_  64
#define NDEATH (B_ - 1)
#define NSORT  512          // NDEATH padded to pow2 for bitonic sort / bsearch
#define RTOL_ 1e-6
#define ATOL_ 1e-8
#define NBLK  256
#define NTHR  512           // 8 waves/block -> 2 waves/SIMD
#define KT    32            // K-tile (per wavegroup), split-K x2

typedef __attribute__((ext_vector_type(4))) double d4_t;

// agent-visible store: relaxed atomic, bypasses L2 -> lands at L3 coherence
// point. No dirty L2 lines => barriers need NO wbl2/inv fences. (R11-verified)
__device__ __forceinline__ void ast(double* p, double v) {
    __hip_atomic_store(p, v, __ATOMIC_RELAXED, __HIP_MEMORY_SCOPE_AGENT);
}
__device__ __forceinline__ double ald(const double* p) {
    return __hip_atomic_load(p, __ATOMIC_RELAXED, __HIP_MEMORY_SCOPE_AGENT);
}
__device__ __forceinline__ unsigned aldu(const unsigned* p) {
    return __hip_atomic_load(p, __ATOMIC_RELAXED, __HIP_MEMORY_SCOPE_AGENT);
}
__device__ __forceinline__ void aadd(unsigned* p) {
    __hip_atomic_fetch_add(p, 1u, __ATOMIC_RELAXED, __HIP_MEMORY_SCOPE_AGENT);
}

// ---------------------------------------------------------------------------
// LDS-only barrier (R15): lgkmcnt(0)+s_barrier. Global prefetches ride across;
// the K-loop's only cross-wave dependency is LDS staging.
// ---------------------------------------------------------------------------
__device__ __forceinline__ void lbar() {
    asm volatile("s_waitcnt lgkmcnt(0)" ::: "memory");
    __builtin_amdgcn_s_barrier();
    asm volatile("" ::: "memory");
}

// ---------------------------------------------------------------------------
// 16-way group barrier (R11-verified protocol). Full __syncthreads REQUIRED:
// the vmcnt(0) drain makes prior ast stores visible before the arrival.
// ---------------------------------------------------------------------------
__device__ __forceinline__ void gbar(unsigned* cnt, unsigned nb) {
    __syncthreads();
    if (threadIdx.x == 0) {
        aadd(cnt);
        while (aldu(cnt) < nb) __builtin_amdgcn_s_sleep(1);
    }
    __syncthreads();
}

// ---------------------------------------------------------------------------
// R16: two-level device barrier. 256-way same-address RMW convoy (~100-200cy
// serialized each) replaced by 16 parallel 16-way group arrivals + a 16-way
// root promoted by group leaders. All blocks release on root==16.
// ---------------------------------------------------------------------------
__device__ __forceinline__ void gbar2(unsigned* gslot, unsigned* root,
                                      int leader) {
    __syncthreads();
    if (threadIdx.x == 0) {
        aadd(gslot);
        if (leader) {
            while (aldu(gslot) < 16u) __builtin_amdgcn_s_sleep(1);
            aadd(root);
        }
        while (aldu(root) < 16u) __builtin_amdgcn_s_sleep(1);
    }
    __syncthreads();
}

// ---------------------------------------------------------------------------
// per-block: bitonic-sort deaths into LDS, emit sorted tolerance windows.
// ---------------------------------------------------------------------------
__device__ void sort_windows(const float* __restrict__ deaths,
                             double* sd, double* slo, double* shi, int t) {
    if (t < NSORT) sd[t] = (t < NDEATH) ? (double)deaths[t] : 1e300;
    __syncthreads();
    for (int k = 2; k <= NSORT; k <<= 1) {
        for (int j = k >> 1; j > 0; j >>= 1) {
            if (t < 256) {
                int l = ((t & ~(j - 1)) << 1) | (t & (j - 1));   // pair (l, l+j)
                int p = l + j;
                bool up = ((l & k) == 0);
                double a = sd[l], b = sd[p];
                if ((a > b) == up) { sd[l] = b; sd[p] = a; }
            }
            __syncthreads();
        }
    }
    if (t < NSORT) {
        double d = sd[t];
        double w = ATOL_ + RTOL_ * fabs(d);
        slo[t] = d - w;
        shi[t] = d + w;
    }
    __syncthreads();
}

// ---------------------------------------------------------------------------
// f64 MFMA GEMM phase, R16: split-K x2 across wavegroups; A staged via LDS
// (depth-3 register prefetch -> ~2-iter latency cover); B loaded DIRECT from
// global to registers (lanes 0-15 read consecutive cols = coalesced; per-wave
// private -> zero barrier coupling); two accumulators split the 8-deep MFMA
// dependency chain. One lgkm-only barrier per K-tile.
// ---------------------------------------------------------------------------
template <typename TIN, bool RELU>
__device__ void gemm_dev(const TIN* __restrict__ A, const float* __restrict__ W,
                         const float* __restrict__ bias, double* __restrict__ C,
                         int N, int K, int tile, int t,
                         double (&As)[2][2][KT][33]) {
    const int lane  = t & 63;
    const int wave4 = (t >> 6) & 3;     // quarter selector (same for both wg)
    const int w2    = t >> 8;           // wavegroup = K-half
    const int tg    = t & 255;          // 256-thread-local id for staging map
    const int wm    = wave4 & 1, wn = wave4 >> 1;
    const int nbx   = N >> 5;
    const int row0  = (tile / nbx) << 5;
    const int col0  = (tile % nbx) << 5;

    const int akk   = tg & 31;          // k within A tile
    const int amm   = tg >> 5;          // base row (rows amm+8p, p=0..3)
    const int kbase = w2 * (K >> 1);
    const int nkt   = K >> 6;           // K-tiles per wavegroup

    const int mrow  = wm * 16 + (lane & 15);
    const int ncol  = wn * 16 + (lane & 15);
    const int kq    = lane >> 4;

    TIN   ar[3][4];
    float br[3][8];

    auto load_a = [&](int rs, int kt) {
        const int k0 = kbase + (kt << 5);
        #pragma unroll
        for (int p = 0; p < 4; ++p)
            ar[rs][p] = A[(size_t)(row0 + amm + 8 * p) * K + k0 + akk];
    };
    auto load_b = [&](int rs, int kt) {
        const int k0 = kbase + (kt << 5);
        const float* wp = W + (size_t)(k0 + kq) * N + col0 + ncol;
        #pragma unroll
        for (int ks = 0; ks < 8; ++ks)
            br[rs][ks] = wp[(size_t)(4 * ks) * N];
    };
    auto stage_a = [&](int rs, int buf) {
        #pragma unroll
        for (int p = 0; p < 4; ++p)
            As[w2][buf][akk][amm + 8 * p] = (double)ar[rs][p];
    };

    load_a(0, 0); load_b(0, 0);
    if (nkt > 1) { load_a(1, 1); load_b(1, 1); }
    if (nkt > 2) { load_a(2, 2); load_b(2, 2); }
    stage_a(0, 0);
    lbar();

    d4_t c4a = {0.0, 0.0, 0.0, 0.0};
    d4_t c4b = {0.0, 0.0, 0.0, 0.0};

    for (int kt = 0; kt < nkt; ++kt) {
        const int cur = kt & 1;
        const int rs  = kt % 3;
        #pragma unroll
        for (int ks = 0; ks < 4; ++ks) {
            double av = As[w2][cur][ks * 4 + kq][mrow];
            c4a = __builtin_amdgcn_mfma_f64_16x16x4f64(av, (double)br[rs][ks],
                                                       c4a, 0, 0, 0);
        }
        #pragma unroll
        for (int ks = 4; ks < 8; ++ks) {
            double av = As[w2][cur][ks * 4 + kq][mrow];
            c4b = __builtin_amdgcn_mfma_f64_16x16x4f64(av, (double)br[rs][ks],
                                                       c4b, 0, 0, 0);
        }
        // slot rs fully consumed (A staged last iter, B read above) -> refill
        if (kt + 3 < nkt) { load_a(rs, kt + 3); load_b(rs, kt + 3); }
        if (kt + 1 < nkt) stage_a((kt + 1) % 3, cur ^ 1); // disjoint buffer
        lbar();                                           // lgkm-only
    }

    d4_t c4 = c4a + c4b;

    // combine wavegroup partials: wg1 publishes, wg0 adds + epilogue.
    // cEx aliases As (all K-loop reads fenced by the final loop barrier).
    double (*cEx)[16][17] = (double (*)[16][17])(&As[0][0][0][0]);
    const int r4 = (lane >> 4) * 4;
    if (w2 == 1) {
        #pragma unroll
        for (int r = 0; r < 4; ++r)
            cEx[wave4][r4 + r][lane & 15] = c4[r];
    }
    lbar();
    if (w2 == 0) {
        #pragma unroll
        for (int r = 0; r < 4; ++r) {
            int row = row0 + wm * 16 + r4 + r;
            int col = col0 + wn * 16 + (lane & 15);
            double v = c4[r] + cEx[wave4][r4 + r][lane & 15] + (double)bias[col];
            if (RELU) v = v > 0.0 ? v : 0.0;
            ast(&C[(size_t)row * N + col], v);
        }
    }
}

// ---------------------------------------------------------------------------
// column c: mean + target-MSE partial + compactness partial -> global slots
// ---------------------------------------------------------------------------
__device__ void mc_dev(const float* __restrict__ target,
                       const double* __restrict__ y,
                       double* __restrict__ t_part, double* __restrict__ c_part,
                       int c, int t) {
    const int wave = t >> 6, lane = t & 63;
    double v = y[(size_t)t * OUT_ + c];
    double s = v;
    for (int off = 32; off; off >>= 1) s += __shfl_down(s, off);
    __shared__ double swm[8];
    __shared__ double smean;
    if (lane == 0) swm[wave] = s;
    __syncthreads();
    if (t == 0) {
        double m = 0.0;
        #pragma unroll
        for (int w = 0; w < 8; ++w) m += swm[w];
        smean = m / (double)B_;
    }
    __syncthreads();
    double m = smean;
    double d = (double)target[(size_t)t * OUT_ + c] - v;
    double t_s = d * d;
    double c_s = fabs(v - m);
    for (int off = 32; off; off >>= 1) {
        t_s += __shfl_down(t_s, off);
        c_s += __shfl_down(c_s, off);
    }
    __shared__ double st[8], sc[8];
    if (lane == 0) { st[wave] = t_s; sc[wave] = c_s; }
    __syncthreads();
    if (t == 0) {
        double ts = 0.0, cs = 0.0;
        #pragma unroll
        for (int w = 0; w < 8; ++w) { ts += st[w]; cs += sc[w]; }
        ast(&t_part[c], ts);
        ast(&c_part[c], cs);
    }
}

// ---------------------------------------------------------------------------
// pdist + sorted-window match. Block b: rows b and 510-b (512 pairs, balanced).
// ---------------------------------------------------------------------------
__device__ __forceinline__ double pair_val(const double* __restrict__ yrow_s,
                                           const double* __restrict__ yj,
                                           const double* __restrict__ slo,
                                           const double* __restrict__ shi) {
    double s = 0.0;
    #pragma unroll
    for (int d = 0; d < OUT_; d += 2) {
        double2 v = *(const double2*)(yj + d);
        double d0 = yrow_s[d]     - v.x;
        double d1 = yrow_s[d + 1] - v.y;
        s = fma(d0, d0, s);
        s = fma(d1, d1, s);
    }
    double pd = sqrt(s);
    int pos = 0;
    #pragma unroll
    for (int step = NSORT / 2; step; step >>= 1) {
        if (slo[pos + step - 1] <= pd) pos += step;
    }
    bool m = (pos > 0) && (shi[pos - 1] >= pd);
    return m ? pd : 0.0;
}

__device__ void pdist_dev(const double* __restrict__ y,
                          double* __restrict__ hom_part, int bid, int t,
                          double* yA, double* yB,
                          const double* slo, const double* shi) {
    const int iA = bid;
    const int iB = 510 - bid;     // == iA when bid == 255
    if (t < OUT_)            yA[t]        = y[(size_t)iA * OUT_ + t];
    else if (t < 2 * OUT_)   yB[t - OUT_] = y[(size_t)iB * OUT_ + (t - OUT_)];
    __syncthreads();

    double local = 0.0;
    for (int j = iA + 1 + t; j < B_; j += NTHR)
        local += pair_val(yA, y + (size_t)j * OUT_, slo, shi);
    if (iB != iA)
        for (int j = iB + 1 + t; j < B_; j += NTHR)
            local += pair_val(yB, y + (size_t)j * OUT_, slo, shi);

    for (int off = 32; off; off >>= 1) local += __shfl_down(local, off);
    __shared__ double sw[8];
    int wave = t >> 6, lane = t & 63;
    if (lane == 0) sw[wave] = local;
    __syncthreads();
    if (t == 0) {
        double s = 0.0;
        #pragma unroll
        for (int w = 0; w < 8; ++w) s += sw[w];
        ast(&hom_part[bid], s);
    }
}

// ---------------------------------------------------------------------------
// single fused persistent kernel, R16: 256 blocks x 512 threads.
// 16 groups of 16 blocks; group g owns row-strip g through the MLP; P0..P2
// sync with GROUP-LOCAL 16-arrival barriers; TWO-LEVEL device barrier before
// pdist; TWO-LEVEL finalize arrivals with block 0 as fixed finalizer.
// Counters (uints): grp g slot p -> cnt[g*32+p] (p=0..4); pdist root cnt[512];
// finalize root cnt[513]. Window broadcast: wbc[0..511]=lo, wbc[512..1023]=hi.
// ---------------------------------------------------------------------------
__global__ __launch_bounds__(NTHR) void fused_k(
    const float* __restrict__ batch, const float* __restrict__ target,
    const float* __restrict__ W1, const float* __restrict__ b1,
    const float* __restrict__ W2, const float* __restrict__ b2,
    const float* __restrict__ W3, const float* __restrict__ b3,
    const float* __restrict__ Wout, const float* __restrict__ bout,
    const float* __restrict__ deaths, float* __restrict__ out,
    double* __restrict__ hA, double* __restrict__ hB,
    double* __restrict__ hC, double* __restrict__ yv,
    double* __restrict__ hom_part, double* __restrict__ t_part,
    double* __restrict__ c_part, unsigned* __restrict__ cnt,
    double* __restrict__ wbc) {
    const int bid = blockIdx.x;
    const int t   = threadIdx.x;
    const int g   = bid >> 4;     // group = row-strip
    const int c   = bid & 15;     // col-tile within group
    unsigned* gc  = cnt + g * 32; // group-private counter line

    __shared__ double As[2][2][KT][33];
    __shared__ double slo[NSORT], shi[NSORT];
    __shared__ double yA[OUT_], yB[OUT_];
    double* sd = &As[0][0][0][0];             // sort scratch alias (512 dbl)

    // P0..P2: three 512x512 GEMMs; tile = bid (row0=32g, col0=32c).
    gemm_dev<float,  true>(batch, W1, b1, hA, H_, IN_, bid, t, As);
    gbar(&gc[0], 16);
    gemm_dev<double, true>(hA, W2, b2, hB, H_, H_, bid, t, As);
    gbar(&gc[1], 16);
    gemm_dev<double, true>(hB, W3, b3, hC, H_, H_, bid, t, As);
    gbar(&gc[2], 16);

    // P3: Wout tile g*2+c on c<2 (row-strip g -> group-local dep); c>=2 sort.
    // bid==2 publishes the sorted windows for the c<2 blocks.
    if (c < 2) {
        gemm_dev<double, false>(hC, Wout, bout, yv, OUT_, H_, g * 2 + c, t, As);
    } else {
        sort_windows(deaths, sd, slo, shi, t);
        if (bid == 2 && t < NSORT) {
            ast(&wbc[t],         slo[t]);
            ast(&wbc[NSORT + t], shi[t]);
        }
    }

    // two-level device barrier: pdist needs all of yv + window broadcast
    gbar2(&gc[3], &cnt[512], c == 0);
    if (c < 2) {
        if (t < NSORT) {
            slo[t] = ald(&wbc[t]);
            shi[t] = ald(&wbc[NSORT + t]);
        }
        __syncthreads();
    }

    // P4: pdist on all 256 blocks; mean/MSE/compactness on blocks 0..63
    pdist_dev(yv, hom_part, bid, t, yA, yB, slo, shi);
    if (bid < OUT_) mc_dev(target, yv, t_part, c_part, bid, t);

    // P5: two-level finalize arrivals; block 0 is the fixed finalizer.
    __syncthreads();   // vmcnt(0) drain: part stores visible before arrival
    if (t == 0) {
        aadd(&gc[4]);
        if (c == 0) {
            while (aldu(&gc[4]) < 16u) __builtin_amdgcn_s_sleep(1);
            aadd(&cnt[513]);
        }
    }
    if (bid != 0) return;
    if (t == 0)
        while (aldu(&cnt[513]) < 16u) __builtin_amdgcn_s_sleep(1);
    __syncthreads();

    {
        double h = 0.0, tp = 0.0, cp = 0.0;
        if (t < NBLK) h = ald(&hom_part[t]);
        if (t < OUT_) { tp = ald(&t_part[t]); cp = ald(&c_part[t]); }
        for (int off = 32; off; off >>= 1) {
            h  += __shfl_down(h,  off);
            tp += __shfl_down(tp, off);
            cp += __shfl_down(cp, off);
        }
        __shared__ double sh[8], stp[8], scp[8];
        int wave = t >> 6, lane = t & 63;
        if (lane == 0) { sh[wave] = h; stp[wave] = tp; scp[wave] = cp; }
        __syncthreads();
        if (t == 0) {
            double hs = 0.0, ts = 0.0, cs = 0.0;
            #pragma unroll
            for (int w = 0; w < 8; ++w) {
                hs += sh[w]; ts += stp[w]; cs += scp[w];
            }
            out[0] = (float)(ts / (double)(B_ * OUT_) + hs + 0.01 * cs);
        }
    }
}

extern "C" void kernel_launch(void* const* d_in, const int* in_sizes, int n_in,
                              void* d_out, int out_size, void* d_ws, size_t ws_size,
                              hipStream_t stream) {
    const float* batch  = (const float*)d_in[0];
    const float* target = (const float*)d_in[1];
    const float* W1     = (const float*)d_in[2];
    const float* b1     = (const float*)d_in[3];
    const float* W2     = (const float*)d_in[4];
    const float* b2     = (const float*)d_in[5];
    const float* W3     = (const float*)d_in[6];
    const float* b3     = (const float*)d_in[7];
    const float* Wout   = (const float*)d_in[8];
    const float* bout   = (const float*)d_in[9];
    const float* deaths = (const float*)d_in[10];
    float* out = (float*)d_out;

    double* hA       = (double*)d_ws;              // 512*512
    double* hB       = hA + (size_t)B_ * H_;       // 512*512
    double* hC       = hB + (size_t)B_ * H_;       // 512*512
    double* yv       = hC + (size_t)B_ * H_;       // 512*64
    double* hom_part = yv + (size_t)B_ * OUT_;     // 256
    double* t_part   = hom_part + NBLK;            // 64
    double* c_part   = t_part + OUT_;              // 64
    unsigned* cnt    = (unsigned*)(c_part + OUT_); // 576 uints
    double* wbc      = (double*)(cnt + 576);       // 1024 doubles (lo|hi)

    hipMemsetAsync(cnt, 0, 576 * sizeof(unsigned), stream);

    fused_k<<<dim3(NBLK), dim3(NTHR), 0, stream>>>(
        batch, target, W1, b1, W2, b2, W3, b3, Wout, bout, deaths, out,
        hA, hB, hC, yv, hom_part, t_part, c_part, cnt, wbc);
}